// Round 5
// baseline (263.868 us; speedup 1.0000x reference)
//
#include <hip/hip_runtime.h>
#include <math.h>

#define HALF 64
#define LN_EPS 1e-5f
#define SA_CAP 640   // staged edges per block (10 KB f4); Poisson(256)+24sigma

// ---------------------------------------------------------------------------
// histogram of dst; atomic return value IS the edge's rank in its bucket.
// 8 edges/thread, phase-separated (loads -> 8 independent atomics -> stores)
// so the ~600cy L3 atomic latency overlaps 8-deep per thread.
// ---------------------------------------------------------------------------
__global__ void __launch_bounds__(256, 4) hist_kernel(
    const int* __restrict__ dst, int* __restrict__ cursor,
    int* __restrict__ rank, int E)
{
    const int e8 = (blockIdx.x * 256 + threadIdx.x) * 8;
    if (e8 + 7 < E) {
        const int4 d0 = *(const int4*)(dst + e8);
        const int4 d1 = *(const int4*)(dst + e8 + 4);
        int4 r0, r1;
        r0.x = atomicAdd(&cursor[d0.x], 1);
        r0.y = atomicAdd(&cursor[d0.y], 1);
        r0.z = atomicAdd(&cursor[d0.z], 1);
        r0.w = atomicAdd(&cursor[d0.w], 1);
        r1.x = atomicAdd(&cursor[d1.x], 1);
        r1.y = atomicAdd(&cursor[d1.y], 1);
        r1.z = atomicAdd(&cursor[d1.z], 1);
        r1.w = atomicAdd(&cursor[d1.w], 1);
        *(int4*)(rank + e8)     = r0;
        *(int4*)(rank + e8 + 4) = r1;
    } else {
        for (int e = e8; e < E; ++e) rank[e] = atomicAdd(&cursor[dst[e]], 1);
    }
}

// ---------------------------------------------------------------------------
// PARALLEL exclusive scan (decoupled lookback) -> offsets[]. Block 0 wave 0
// also computes the analytic-LN constants fp[0..13].
// ---------------------------------------------------------------------------
__global__ void __launch_bounds__(1024) scan_kernel(
    const int* __restrict__ cursor, int* __restrict__ offsets,
    int* __restrict__ stat,
    const float* __restrict__ W1, const float* __restrict__ b1,
    float* __restrict__ fp, int N)
{
    const int t = threadIdx.x;
    const int b = blockIdx.x;
    if (b == 0 && t < 64) {
        const float w0 = W1[t], w1 = W1[HALF + t], w2 = W1[2 * HALF + t], bb = b1[t];
        float v[14] = { w0, w1, w2, bb,
                        w0 * w0, w0 * w1, w0 * w2, w1 * w1, w1 * w2, w2 * w2,
                        w0 * bb, w1 * bb, w2 * bb, bb * bb };
#pragma unroll
        for (int j = 0; j < 14; ++j) {
            float s = v[j];
#pragma unroll
            for (int off = 32; off; off >>= 1) s += __shfl_down(s, off, 64);
            if (t == 0) fp[j] = s * (1.0f / 64.0f);
        }
    }

    __shared__ int wtot[16];
    __shared__ int wexc[16];
    __shared__ int stot;
    __shared__ int sPref;
    const int w = t >> 6, lane = t & 63;

    const int i0 = b * 4096 + t * 4;
    int c[4];
    if (i0 + 3 < N) {
        *(int4*)c = *(const int4*)(cursor + i0);
    } else {
#pragma unroll
        for (int j = 0; j < 4; ++j) c[j] = (i0 + j < N) ? cursor[i0 + j] : 0;
    }
    const int s = c[0] + c[1] + c[2] + c[3];
    int incl = s;
#pragma unroll
    for (int off = 1; off < 64; off <<= 1) {
        const int v = __shfl_up(incl, off, 64);
        if (lane >= off) incl += v;
    }
    if (lane == 63) wtot[w] = incl;
    __syncthreads();
    if (t < 16) {
        const int v = wtot[t];
        int inc2 = v;
#pragma unroll
        for (int off = 1; off < 16; off <<= 1) {
            const int u = __shfl_up(inc2, off, 64);
            if (t >= off) inc2 += u;
        }
        wexc[t] = inc2 - v;
        if (t == 15) stot = inc2;
    }
    __syncthreads();

    if (t == 0) {
        const int S = stot;
        if (b == 0) {
            sPref = 0;
            __hip_atomic_store(&stat[0], (S << 2) | 2, __ATOMIC_RELEASE,
                               __HIP_MEMORY_SCOPE_AGENT);
        } else {
            __hip_atomic_store(&stat[b], (S << 2) | 1, __ATOMIC_RELEASE,
                               __HIP_MEMORY_SCOPE_AGENT);
            int running = 0;
            int j = b - 1;
            while (true) {
                const int v = __hip_atomic_load(&stat[j], __ATOMIC_ACQUIRE,
                                                __HIP_MEMORY_SCOPE_AGENT);
                const int st = v & 3;
                if (st == 0) continue;          // predecessor not published yet
                running += v >> 2;
                if (st == 2) break;             // hit a full prefix
                --j;
            }
            sPref = running;
            __hip_atomic_store(&stat[b], ((running + S) << 2) | 2,
                               __ATOMIC_RELEASE, __HIP_MEMORY_SCOPE_AGENT);
        }
    }
    __syncthreads();

    int run = sPref + wexc[w] + (incl - s);
#pragma unroll
    for (int j = 0; j < 4; ++j) {
        const int i = i0 + j;
        if (i < N) offsets[i] = run;
        run += c[j];
    }
    if (t == 0 && b == (int)gridDim.x - 1) offsets[N] = sPref + stot;
}

// ---------------------------------------------------------------------------
// fill_idx (atomic-free): srcidx[offsets[dst]+rank] = src. 8 edges/thread,
// phase-separated (streamed loads -> 8 independent offset gathers -> 8
// scattered 4B stores) for gather-latency overlap.
// ---------------------------------------------------------------------------
__global__ void __launch_bounds__(256, 4) fillidx_kernel(
    const int* __restrict__ ei, const int* __restrict__ rank,
    const int* __restrict__ offsets, int* __restrict__ srcidx, int E)
{
    const int e8 = (blockIdx.x * 256 + threadIdx.x) * 8;
    if (e8 >= E) return;
    if (e8 + 7 < E) {
        const int4 s0 = *(const int4*)(ei + e8);
        const int4 s1 = *(const int4*)(ei + e8 + 4);
        const int4 d0 = *(const int4*)(ei + E + e8);
        const int4 d1 = *(const int4*)(ei + E + e8 + 4);
        const int4 r0 = *(const int4*)(rank + e8);
        const int4 r1 = *(const int4*)(rank + e8 + 4);
        const int o0 = offsets[d0.x];
        const int o1 = offsets[d0.y];
        const int o2 = offsets[d0.z];
        const int o3 = offsets[d0.w];
        const int o4 = offsets[d1.x];
        const int o5 = offsets[d1.y];
        const int o6 = offsets[d1.z];
        const int o7 = offsets[d1.w];
        srcidx[o0 + r0.x] = s0.x;
        srcidx[o1 + r0.y] = s0.y;
        srcidx[o2 + r0.z] = s0.z;
        srcidx[o3 + r0.w] = s0.w;
        srcidx[o4 + r1.x] = s1.x;
        srcidx[o5 + r1.y] = s1.y;
        srcidx[o6 + r1.z] = s1.z;
        srcidx[o7 + r1.w] = s1.w;
    } else {
        for (int e = e8; e < E; ++e)
            srcidx[offsets[ei[E + e]] + rank[e]] = ei[e];
    }
}

// ---------------------------------------------------------------------------
// FUSED geometry+node+out kernel v6.
// New vs v5 (which was VALUBusy 94.7% -> pure issue-bound):
//  * GELU via 512-entry (value,slope) LDS LUT + lerp, built per block from
//    the EXACT erf-GELU (more accurate than the old tanh approx). Removes
//    v_exp_f32 + v_rcp_f32 (2 quarter-rate trans = ~16cy/edge of VALU issue)
//    from the per-edge path; LUT gather rides the idle LDS pipe.
//    Domain: x is an exact LN output with gamma=1,beta=0 => |x| <= sqrt(63)
//    < 8, so [-8,8) covers all values; med3 clamp guards regardless.
//  * Last-chunk peel: full chunks run guard-free (no idx<wcnt cndmask).
// ---------------------------------------------------------------------------
__global__ void __launch_bounds__(256, 4) nodeout_kernel(
    const int* __restrict__ srcidx,      // [E+16] CSR-ordered src ids
    const int* __restrict__ offsets,     // [N+1]
    const float* __restrict__ pos,
    const float* __restrict__ W1, const float* __restrict__ b1,
    const float* __restrict__ ln_g, const float* __restrict__ ln_b,
    const float* __restrict__ W2, const float* __restrict__ b2,
    const float* __restrict__ fp,
    float* __restrict__ out, int N)
{
    __shared__ float4 sA[SA_CAP + 8];    // 10.4 KB geometry tile (+pad)
    __shared__ float  sh[16 * 64];       // 4 KB mean rows
    __shared__ float2 sLut[512];         // 4 KB gelu (value, slope) table
    __shared__ int    sOff[17];
    __shared__ float4 sPd[16];           // dst positions

    const int tid = threadIdx.x;
    const int lane = tid & 63, w = tid >> 6;
    const int base = blockIdx.x * 16;

    // exact-GELU LUT over [-8,8), step 1/32 (build is off the hot path)
    for (int i = tid; i < 512; i += 256) {
        const float x0 = (float)i * (1.0f / 32.0f) - 8.0f;
        const float v0 = 0.5f * x0 * (1.0f + erff(x0 * 0.70710678f));
        const float x1 = x0 + (1.0f / 32.0f);
        const float v1 = 0.5f * x1 * (1.0f + erff(x1 * 0.70710678f));
        sLut[i] = make_float2(v0, v1 - v0);
    }

    if (tid < 17) sOff[tid] = offsets[(base + tid < N) ? base + tid : N];
    if (tid < 16) {
        const int n = base + tid;
        if (n < N)
            sPd[tid] = make_float4(pos[3 * n], pos[3 * n + 1], pos[3 * n + 2], 0.0f);
    }

    // phase-1 per-lane constants
    const float gl = ln_g[lane];
    const float C0 = gl * (W1[lane]            - fp[0]);
    const float C1 = gl * (W1[HALF + lane]     - fp[1]);
    const float C2 = gl * (W1[2 * HALF + lane] - fp[2]);
    const float C3 = gl * (b1[lane]            - fp[3]);
    const float Bl = ln_b[lane];
    const float b2l = b2[lane];

    // geometry constants (uniform -> SGPRs)
    const float ux = fp[0], uy = fp[1], uz = fp[2], cc = fp[3];
    const float Gxx = fp[4], Gxy = fp[5], Gxz = fp[6];
    const float Gyy = fp[7], Gyz = fp[8], Gzz = fp[9];
    const float px = fp[10], py = fp[11], pz = fp[12], q13 = fp[13];

    const int nend = (base + 16 < N) ? base + 16 : N;
    const int begB = offsets[base];
    const int cntB = offsets[nend] - begB;

    // wave's 4-node CSR bounds
    const int n0 = base + w * 4;
    const int o0 = offsets[(n0     < N) ? n0     : N];
    const int o1 = offsets[(n0 + 1 < N) ? n0 + 1 : N];
    const int o2 = offsets[(n0 + 2 < N) ? n0 + 2 : N];
    const int o3 = offsets[(n0 + 3 < N) ? n0 + 3 : N];
    const int o4 = offsets[(n0 + 4 < N) ? n0 + 4 : N];
    const int c0 = o1 - o0, c1 = o2 - o1, c2 = o3 - o2, c3 = o4 - o3;
    const int e1 = c0, e2 = c0 + c1, e3 = c0 + c1 + c2;
    const int wcnt = c0 + c1 + c2 + c3;
    const float i0 = (c0 > 0) ? 1.0f / (float)c0 : 0.0f;
    const float i1 = (c1 > 0) ? 1.0f / (float)c1 : 0.0f;
    const float i2 = (c2 > 0) ? 1.0f / (float)c2 : 0.0f;
    const float i3 = (c3 > 0) ? 1.0f / (float)c3 : 0.0f;
    const int off = o0 - begB;

    __syncthreads();                      // sOff / sPd / sLut visible

#define GELU_LUT(X, G)                                                      \
    {                                                                       \
        float t = fmaf((X), 32.0f, 256.0f);                                 \
        t = fminf(fmaxf(t, 0.0f), 511.0f);                                  \
        const int ii = (int)t;                                              \
        const float ff = t - (float)ii;                                     \
        const float2 lv = sLut[ii];                                         \
        (G) = fmaf(ff, lv.y, lv.x);                                         \
    }

    // geometry pre-pass for tile [t0, t0+tcnt): 1 edge/thread avg
#define PREPASS(T0, TCNT)                                                   \
    for (int i = tid; i < (TCNT); i += 256) {                               \
        const int slot = begB + (T0) + i;                                   \
        const int s = srcidx[slot];                                         \
        int qd = 0;                                                         \
        _Pragma("unroll")                                                   \
        for (int k = 1; k < 16; ++k) qd += (slot >= sOff[k]) ? 1 : 0;       \
        const float4 pd = sPd[qd];                                          \
        const float rx0 = pd.x - pos[3 * s];                                \
        const float ry0 = pd.y - pos[3 * s + 1];                            \
        const float rz0 = pd.z - pos[3 * s + 2];                            \
        const float dist = sqrtf(rx0 * rx0 + ry0 * ry0 + rz0 * rz0);        \
        const float invd = 1.0f / (dist + 1e-6f);                           \
        const float rx = rx0 * invd, ry = ry0 * invd, rz = rz0 * invd;      \
        const float mu  = fmaf(ux, rx, fmaf(uy, ry, fmaf(uz, rz, cc)));     \
        const float ev2 = Gxx * rx * rx + Gyy * ry * ry + Gzz * rz * rz     \
                        + 2.0f * (Gxy * rx * ry + Gxz * rx * rz             \
                                  + Gyz * ry * rz + px * rx + py * ry       \
                                  + pz * rz) + q13;                         \
        const float rstd = rsqrtf(ev2 - mu * mu + LN_EPS);                  \
        sA[i] = make_float4(rx * rstd, ry * rstd, rz * rstd, rstd);         \
    }

#define EDGE_X(AJ, X)                                                       \
    const float X = fmaf(C0, (AJ).x, fmaf(C1, (AJ).y,                       \
                      fmaf(C2, (AJ).z, fmaf(C3, (AJ).w, Bl))));

    if (cntB <= SA_CAP) {
        // ---- fast path ----
        PREPASS(0, cntB)
        __syncthreads();

        int q = 0, nextEnd = e1;
        float accA = 0.0f, accB = 0.0f;
#define FLUSH_ROW()                                                         \
        {                                                                   \
            const float inv = (q == 0) ? i0 : (q == 1) ? i1 : (q == 2) ? i2 : i3; \
            sh[(w * 4 + q) * 64 + lane] = (accA + accB) * inv;              \
            accA = 0.0f; accB = 0.0f; ++q;                                  \
            nextEnd = (q == 1) ? e2 : (q == 2) ? e3 : (q == 3) ? wcnt : 0x7fffffff; \
        }
        const int wfull = wcnt & ~7;     // guard-free region
        for (int i = 0; i < wfull; i += 8) {
            float4 aa[8];
#pragma unroll
            for (int j = 0; j < 8; ++j) aa[j] = sA[off + i + j];
#pragma unroll
            for (int j = 0; j < 8; ++j) {
                const int idx = i + j;
                while (q < 4 && idx == nextEnd) FLUSH_ROW();
                EDGE_X(aa[j], x)
                float g; GELU_LUT(x, g)
                if (j & 1) accB += g; else accA += g;
            }
        }
        if (wfull < wcnt) {              // single guarded tail chunk
            float4 aa[8];
#pragma unroll
            for (int j = 0; j < 8; ++j) aa[j] = sA[off + wfull + j];
#pragma unroll
            for (int j = 0; j < 8; ++j) {
                const int idx = wfull + j;
                while (q < 4 && idx == nextEnd) FLUSH_ROW();
                EDGE_X(aa[j], x)
                float g; GELU_LUT(x, g)
                const float gm = (idx < wcnt) ? g : 0.0f;
                if (j & 1) accB += gm; else accA += gm;
            }
        }
        while (q < 4) FLUSH_ROW();
#undef FLUSH_ROW
    } else {
        // ---- fallback: tiled (block-uniform, astronomically rare) ----
        float fa0 = 0.0f, fa1 = 0.0f, fa2 = 0.0f, fa3 = 0.0f;
        for (int t0 = 0; t0 < cntB; t0 += SA_CAP) {
            const int tcnt = (cntB - t0 < SA_CAP) ? cntB - t0 : SA_CAP;
            PREPASS(t0, tcnt)
            __syncthreads();
#define ACCUM(FA, LO, HI)                                                   \
            {                                                               \
                int lo = off + (LO); if (lo < t0) lo = t0;                  \
                int hi = off + (HI); if (hi > t0 + tcnt) hi = t0 + tcnt;    \
                for (int i = lo; i < hi; ++i) {                             \
                    const float4 a = sA[i - t0];                            \
                    EDGE_X(a, x)                                            \
                    float g; GELU_LUT(x, g)                                 \
                    FA += g;                                                \
                }                                                           \
            }
            ACCUM(fa0, 0,  e1)
            ACCUM(fa1, e1, e2)
            ACCUM(fa2, e2, e3)
            ACCUM(fa3, e3, wcnt)
#undef ACCUM
            __syncthreads();             // protect sA for next tile
        }
        sh[(w * 4 + 0) * 64 + lane] = fa0 * i0;
        sh[(w * 4 + 1) * 64 + lane] = fa1 * i1;
        sh[(w * 4 + 2) * 64 + lane] = fa2 * i2;
        sh[(w * 4 + 3) * 64 + lane] = fa3 * i3;
    }
#undef PREPASS
#undef EDGE_X
#undef GELU_LUT

    // keep wcol loads out of phase 1 (register-pressure fence)
    __builtin_amdgcn_sched_barrier(0);

    // Phase 2: lane c owns W2[:,c]; each wave finishes its own 4 nodes.
    float wcol[64];
#pragma unroll
    for (int k = 0; k < 64; ++k) wcol[k] = W2[k * HALF + lane];

#pragma unroll
    for (int qn = 0; qn < 4; ++qn) {
        const int n = n0 + qn;
        if (n < N) {
            const float* shrow = sh + (w * 4 + qn) * 64;
            float oA = 0.0f, oB = 0.0f, oC = 0.0f, oD = 0.0f;
#pragma unroll
            for (int k4 = 0; k4 < 16; ++k4) {
                const float4 hv = *(const float4*)(shrow + k4 * 4);
                oA = fmaf(hv.x, wcol[4 * k4 + 0], oA);
                oB = fmaf(hv.y, wcol[4 * k4 + 1], oB);
                oC = fmaf(hv.z, wcol[4 * k4 + 2], oC);
                oD = fmaf(hv.w, wcol[4 * k4 + 3], oD);
            }
            const int cq = (qn == 0) ? c0 : (qn == 1) ? c1 : (qn == 2) ? c2 : c3;
            const float res = (cq > 0) ? ((oA + oB) + (oC + oD)) + b2l : 0.0f;
            float* orow = out + (size_t)n * (2 * HALF);
            orow[lane] = res;
            orow[HALF + lane] = 0.0f;
        }
    }
}

// ---------------------------------------------------------------------------
extern "C" void kernel_launch(void* const* d_in, const int* in_sizes, int n_in,
                              void* d_out, int out_size, void* d_ws, size_t ws_size,
                              hipStream_t stream) {
    const float* pos = (const float*)d_in[0];
    const int*   ei  = (const int*)d_in[1];
    // d_in[2] = batch (unused)
    const float* W1  = (const float*)d_in[3];
    const float* b1  = (const float*)d_in[4];
    const float* g   = (const float*)d_in[5];
    const float* b   = (const float*)d_in[6];
    const float* W2  = (const float*)d_in[7];
    const float* b2  = (const float*)d_in[8];
    float* out = (float*)d_out;

    const int N = in_sizes[0] / 3;
    const int E = in_sizes[1] / 2;

    // workspace: srcidx[E+16] | cursor[N] | stat[32] | offsets[N+1] | fp[16] | rank[E]
    int* srcidx    = (int*)d_ws;
    int* cursor    = srcidx + E + 16;
    int* stat      = cursor + N;
    int* offsets   = stat + 32;
    float* fparams = (float*)(offsets + N + 1);
    int* rank      = (int*)(fparams + 16);

    const int nb = (N + 4095) / 4096;    // 25 for N=100k (all co-resident)
    const int eb8 = (E / 8 + 255) / 256; // 8-edge/thread grids

    hipMemsetAsync(cursor, 0, (size_t)(N + 32) * sizeof(int), stream);
    hist_kernel<<<eb8, 256, 0, stream>>>(ei + E, cursor, rank, E);
    scan_kernel<<<nb, 1024, 0, stream>>>(cursor, offsets, stat, W1, b1,
                                         fparams, N);
    fillidx_kernel<<<eb8, 256, 0, stream>>>(ei, rank, offsets, srcidx, E);
    nodeout_kernel<<<(N + 15) / 16, 256, 0, stream>>>(srcidx, offsets, pos,
                                                      W1, b1, g, b, W2, b2,
                                                      fparams, out, N);
}